// Round 1
// baseline (135.538 us; speedup 1.0000x reference)
//
#include <hip/hip_runtime.h>

#define SP_EPS 1e-6f

// One wave (64 lanes) per vertex. Lane = feature column f (F == 64).
// Lanes 0..31 compute the 3 radius-bin Gaussian weights for their neighbor k;
// the k-loop broadcasts (idx, w0, w1, w2) from lane k and every lane
// accumulates 3 weighted feature sums + the 3 weight denominators.
__global__ __launch_bounds__(256) void softpixel_radius_kernel(
    const float* __restrict__ feat,     // (V, 64)
    const float* __restrict__ distsq,   // (V, 32)
    const int*   __restrict__ nidx,     // (V, 32)
    const float* __restrict__ ls_ptr,   // scalar
    float*       __restrict__ out,      // (V, 192)
    int V)
{
    const int lane = threadIdx.x & 63;
    const int wv   = threadIdx.x >> 6;
    const int v    = blockIdx.x * 4 + wv;
    if (v >= V) return;

    const float ls      = ls_ptr[0];
    const float scaler  = 10.0f * ls * 3.0f;   // 10 * length_scale * SUBDIVISIONS
    const float inv_ls  = 1.0f / ls;

    // Per-neighbor weights, computed once in lanes 0..31.
    float w0 = 0.0f, w1 = 0.0f, w2 = 0.0f;
    int   nb = 0;
    if (lane < 32) {
        const float dsq = distsq[v * 32 + lane];
        nb = nidx[v * 32 + lane];
        const float d  = sqrtf(dsq + SP_EPS);
        const float t1 = d - inv_ls;           // offset = 1/ls
        const float t2 = d - 2.0f * inv_ls;    // offset = 2/ls
        w0 = __expf(-scaler * d  * d);
        w1 = __expf(-scaler * t1 * t1);
        w2 = __expf(-scaler * t2 * t2);
    }

    float a0 = 0.0f, a1 = 0.0f, a2 = 0.0f;
    float s0 = SP_EPS, s1 = SP_EPS, s2 = SP_EPS;   // den = sum(w) + eps

    #pragma unroll
    for (int k = 0; k < 32; ++k) {
        const int   ik = __shfl(nb, k, 64);
        const float u0 = __shfl(w0, k, 64);
        const float u1 = __shfl(w1, k, 64);
        const float u2 = __shfl(w2, k, 64);
        const float f  = feat[ik * 64 + lane];     // coalesced 256B row load
        a0 = fmaf(u0, f, a0);
        a1 = fmaf(u1, f, a1);
        a2 = fmaf(u2, f, a2);
        s0 += u0; s1 += u1; s2 += u2;
    }

    float* o = out + v * 192 + lane;
    o[0]   = a0 / s0;
    o[64]  = a1 / s1;
    o[128] = a2 / s2;
}

extern "C" void kernel_launch(void* const* d_in, const int* in_sizes, int n_in,
                              void* d_out, int out_size, void* d_ws, size_t ws_size,
                              hipStream_t stream) {
    const float* feat   = (const float*)d_in[0];   // (V, 64)
    const float* distsq = (const float*)d_in[1];   // (V, 32)
    const int*   nidx   = (const int*)d_in[2];     // (V, 32)
    const float* ls     = (const float*)d_in[3];   // scalar

    const int V = in_sizes[1] / 32;                // distsq has V*32 elements
    float* out = (float*)d_out;

    const int waves_per_block = 4;                 // 256 threads
    const int grid = (V + waves_per_block - 1) / waves_per_block;
    softpixel_radius_kernel<<<grid, 256, 0, stream>>>(feat, distsq, nidx, ls, out, V);
}

// Round 2
// 75.337 us; speedup vs baseline: 1.7991x; 1.7991x over previous
//
#include <hip/hip_runtime.h>

#define SP_EPS 1e-6f

__device__ __forceinline__ unsigned short bf16_rne(float x) {
    unsigned u = __float_as_uint(x);
    unsigned r = u + 0x7fffu + ((u >> 16) & 1u);
    return (unsigned short)(r >> 16);
}

// features f32 (V,64) -> bf16 (V,64) in workspace. 4 floats/thread.
__global__ __launch_bounds__(256) void f32_to_bf16_kernel(
    const float* __restrict__ in, unsigned short* __restrict__ outb, int n4)
{
    int i = blockIdx.x * 256 + threadIdx.x;
    if (i >= n4) return;
    const float4 v = ((const float4*)in)[i];
    ushort4 o;
    o.x = bf16_rne(v.x);
    o.y = bf16_rne(v.y);
    o.z = bf16_rne(v.z);
    o.w = bf16_rne(v.w);
    ((ushort4*)outb)[i] = o;
}

// One wave per vertex, split in 2 half-waves. Lane = (h, j): h = neighbor-slot
// parity, j = feature pair (2j, 2j+1). Weights+index packed as float4 in LDS,
// broadcast via one ds_read_b128 per neighbor-pair iteration.
__global__ __launch_bounds__(256) void softpixel_bf16_kernel(
    const unsigned short* __restrict__ fb,   // (V, 64) bf16
    const float* __restrict__ distsq,        // (V, 32)
    const int*   __restrict__ nidx,          // (V, 32)
    const float* __restrict__ ls_ptr,
    float*       __restrict__ out,           // (V, 192)
    int V)
{
    __shared__ float4 wbuf[4][32];
    const int lane = threadIdx.x & 63;
    const int wv   = threadIdx.x >> 6;
    const int v    = blockIdx.x * 4 + wv;
    const int h    = lane >> 5;
    const int j    = lane & 31;
    const bool active = (v < V);

    if (active && h == 0) {
        const float ls     = ls_ptr[0];
        const float scaler = 10.0f * ls * 3.0f;
        const float inv_ls = 1.0f / ls;
        const float dsq = distsq[v * 32 + j];
        const int   nb  = nidx[v * 32 + j];
        const float d   = sqrtf(dsq + SP_EPS);
        const float t1  = d - inv_ls;
        const float t2  = d - 2.0f * inv_ls;
        wbuf[wv][j] = make_float4(__int_as_float(nb),
                                  __expf(-scaler * d  * d),
                                  __expf(-scaler * t1 * t1),
                                  __expf(-scaler * t2 * t2));
    }
    __syncthreads();
    if (!active) return;

    float a0x = 0.f, a0y = 0.f, a1x = 0.f, a1y = 0.f, a2x = 0.f, a2y = 0.f;
    float s0 = 0.f, s1 = 0.f, s2 = 0.f;

    #pragma unroll
    for (int kk = 0; kk < 16; ++kk) {
        const float4 q = wbuf[wv][2 * kk + h];      // ds_read_b128 broadcast
        const int    ik = __float_as_int(q.x);
        const unsigned fp = *(const unsigned*)(fb + (size_t)ik * 64 + 2 * j);
        const float f0 = __uint_as_float(fp << 16);          // feature 2j
        const float f1 = __uint_as_float(fp & 0xffff0000u);  // feature 2j+1
        a0x = fmaf(q.y, f0, a0x);  a0y = fmaf(q.y, f1, a0y);
        a1x = fmaf(q.z, f0, a1x);  a1y = fmaf(q.z, f1, a1y);
        a2x = fmaf(q.w, f0, a2x);  a2y = fmaf(q.w, f1, a2y);
        s0 += q.y;  s1 += q.z;  s2 += q.w;
    }

    // combine the two half-waves
    a0x += __shfl_xor(a0x, 32, 64);  a0y += __shfl_xor(a0y, 32, 64);
    a1x += __shfl_xor(a1x, 32, 64);  a1y += __shfl_xor(a1y, 32, 64);
    a2x += __shfl_xor(a2x, 32, 64);  a2y += __shfl_xor(a2y, 32, 64);
    s0  += __shfl_xor(s0, 32, 64);
    s1  += __shfl_xor(s1, 32, 64);
    s2  += __shfl_xor(s2, 32, 64);
    s0 += SP_EPS;  s1 += SP_EPS;  s2 += SP_EPS;

    if (h == 0) {
        float* o = out + (size_t)v * 192 + 2 * j;
        *(float2*)(o)       = make_float2(a0x / s0, a0y / s0);
        *(float2*)(o + 64)  = make_float2(a1x / s1, a1y / s1);
        *(float2*)(o + 128) = make_float2(a2x / s2, a2y / s2);
    }
}

// Fallback (fp32 gather) if workspace can't hold the bf16 feature table.
__global__ __launch_bounds__(256) void softpixel_f32_kernel(
    const float* __restrict__ feat,
    const float* __restrict__ distsq,
    const int*   __restrict__ nidx,
    const float* __restrict__ ls_ptr,
    float*       __restrict__ out,
    int V)
{
    const int lane = threadIdx.x & 63;
    const int wv   = threadIdx.x >> 6;
    const int v    = blockIdx.x * 4 + wv;
    if (v >= V) return;

    const float ls     = ls_ptr[0];
    const float scaler = 10.0f * ls * 3.0f;
    const float inv_ls = 1.0f / ls;

    float w0 = 0.f, w1 = 0.f, w2 = 0.f;
    int nb = 0;
    if (lane < 32) {
        const float dsq = distsq[v * 32 + lane];
        nb = nidx[v * 32 + lane];
        const float d  = sqrtf(dsq + SP_EPS);
        const float t1 = d - inv_ls;
        const float t2 = d - 2.0f * inv_ls;
        w0 = __expf(-scaler * d  * d);
        w1 = __expf(-scaler * t1 * t1);
        w2 = __expf(-scaler * t2 * t2);
    }

    float a0 = 0.f, a1 = 0.f, a2 = 0.f;
    float s0 = SP_EPS, s1 = SP_EPS, s2 = SP_EPS;
    #pragma unroll
    for (int k = 0; k < 32; ++k) {
        const int   ik = __shfl(nb, k, 64);
        const float u0 = __shfl(w0, k, 64);
        const float u1 = __shfl(w1, k, 64);
        const float u2 = __shfl(w2, k, 64);
        const float f  = feat[(size_t)ik * 64 + lane];
        a0 = fmaf(u0, f, a0);
        a1 = fmaf(u1, f, a1);
        a2 = fmaf(u2, f, a2);
        s0 += u0; s1 += u1; s2 += u2;
    }
    float* o = out + (size_t)v * 192 + lane;
    o[0]   = a0 / s0;
    o[64]  = a1 / s1;
    o[128] = a2 / s2;
}

extern "C" void kernel_launch(void* const* d_in, const int* in_sizes, int n_in,
                              void* d_out, int out_size, void* d_ws, size_t ws_size,
                              hipStream_t stream) {
    const float* feat   = (const float*)d_in[0];   // (V, 64)
    const float* distsq = (const float*)d_in[1];   // (V, 32)
    const int*   nidx   = (const int*)d_in[2];     // (V, 32)
    const float* ls     = (const float*)d_in[3];   // scalar

    const int V = in_sizes[1] / 32;
    const int F = in_sizes[0] / V;                 // 64
    float* out = (float*)d_out;

    const size_t need = (size_t)V * F * sizeof(unsigned short);
    const int grid = (V + 3) / 4;                  // 4 waves (vertices) / block

    if ((size_t)ws_size >= need && F == 64) {
        unsigned short* fb = (unsigned short*)d_ws;
        const int n4 = V * F / 4;
        f32_to_bf16_kernel<<<(n4 + 255) / 256, 256, 0, stream>>>(feat, fb, n4);
        softpixel_bf16_kernel<<<grid, 256, 0, stream>>>(fb, distsq, nidx, ls, out, V);
    } else {
        softpixel_f32_kernel<<<grid, 256, 0, stream>>>(feat, distsq, nidx, ls, out, V);
    }
}

// Round 3
// 72.430 us; speedup vs baseline: 1.8713x; 1.0401x over previous
//
#include <hip/hip_runtime.h>

#define SP_EPS 1e-6f
typedef float f32x2 __attribute__((ext_vector_type(2)));

__device__ __forceinline__ unsigned short bf16_rne(float x) {
    unsigned u = __float_as_uint(x);
    unsigned r = u + 0x7fffu + ((u >> 16) & 1u);
    return (unsigned short)(r >> 16);
}

// features f32 (V,64) -> bf16 (V,64) in workspace. 4 floats/thread.
__global__ __launch_bounds__(256) void f32_to_bf16_kernel(
    const float* __restrict__ in, unsigned short* __restrict__ outb, int n4)
{
    int i = blockIdx.x * 256 + threadIdx.x;
    if (i >= n4) return;
    const float4 v = ((const float4*)in)[i];
    ushort4 o;
    o.x = bf16_rne(v.x); o.y = bf16_rne(v.y);
    o.z = bf16_rne(v.z); o.w = bf16_rne(v.w);
    ((ushort4*)outb)[i] = o;
}

// One wave per vertex; half-wave h processes neighbor 2kk+h; lane j owns the
// feature pair (2j, 2j+1) packed in one dword of the bf16 table.
// Subdivisions 0,1 accumulate as a packed f32x2 via v_pk_fma_f32 (weight pair
// comes pre-aligned from ds_read_b64; feature scalar replicated via op_sel).
__global__ __launch_bounds__(256) void softpixel_pk_kernel(
    const unsigned short* __restrict__ fb,   // (V, 64) bf16
    const float* __restrict__ distsq,        // (V, 32)
    const int*   __restrict__ nidx,          // (V, 32)
    const float* __restrict__ ls_ptr,
    float*       __restrict__ out,           // (V, 192)
    int V)
{
    __shared__ f32x2 w01buf[4][32];   // (w0, w1) per neighbor
    __shared__ f32x2 iw2buf[4][32];   // (as_float(idx), w2)
    const int lane = threadIdx.x & 63;
    const int wv   = threadIdx.x >> 6;
    const int v    = blockIdx.x * 4 + wv;
    const int h    = lane >> 5;
    const int j    = lane & 31;
    const int vc   = v < V ? v : V - 1;

    const float ls     = ls_ptr[0];
    const float scaler = 30.0f * ls;          // 10 * ls * SUBDIVISIONS
    const float inv_ls = 1.0f / ls;

    // prologue: both halves compute all 32 neighbor weights (redundant, cheap)
    const unsigned dvoff = (unsigned)vc * 32u + (unsigned)j;
    const float dsq = distsq[dvoff];
    const int   nb  = nidx[dvoff];
    const float d   = sqrtf(dsq + SP_EPS);
    const float t1  = d - inv_ls;
    const float t2  = d - 2.0f * inv_ls;
    const float w0  = __expf(-scaler * d  * d);
    const float w1  = __expf(-scaler * t1 * t1);
    const float w2  = __expf(-scaler * t2 * t2);
    if (h == 0) {
        w01buf[wv][j] = (f32x2){w0, w1};
        iw2buf[wv][j] = (f32x2){__int_as_float(nb), w2};
    }

    // denominators: 32-lane butterfly (each half holds the full neighbor set)
    float s0 = w0, s1 = w1, s2 = w2;
    #pragma unroll
    for (int st = 1; st < 32; st <<= 1) {
        s0 += __shfl_xor(s0, st, 64);
        s1 += __shfl_xor(s1, st, 64);
        s2 += __shfl_xor(s2, st, 64);
    }
    s0 += SP_EPS; s1 += SP_EPS; s2 += SP_EPS;
    __syncthreads();

    f32x2 a01_0 = {0.f, 0.f};   // (subdiv0, subdiv1) for feature 2j
    f32x2 a01_1 = {0.f, 0.f};   // (subdiv0, subdiv1) for feature 2j+1
    float a2_0 = 0.f, a2_1 = 0.f;
    const unsigned j4 = (unsigned)(j << 2);

    #pragma unroll
    for (int kk = 0; kk < 16; ++kk) {
        const f32x2 w01 = w01buf[wv][2 * kk + h];
        const f32x2 iw2 = iw2buf[wv][2 * kk + h];
        const int   ik  = __float_as_int(iw2.x);
        const unsigned boff = ((unsigned)ik << 7) + j4;           // row*128B + j*4B
        const unsigned fp = *(const unsigned*)((const char*)fb + boff);
        const float f0 = __uint_as_float(fp << 16);
        const float f1 = __uint_as_float(fp & 0xffff0000u);
        f32x2 f01; f01.x = f0; f01.y = f1;
        // a01_0 += w01 * (f0,f0): src1 low replicated to both halves
        asm("v_pk_fma_f32 %0, %1, %2, %0 op_sel:[0,0,0] op_sel_hi:[1,0,1]"
            : "+v"(a01_0) : "v"(w01), "v"(f01));
        // a01_1 += w01 * (f1,f1): src1 high replicated to both halves
        asm("v_pk_fma_f32 %0, %1, %2, %0 op_sel:[0,1,0] op_sel_hi:[1,1,1]"
            : "+v"(a01_1) : "v"(w01), "v"(f01));
        a2_0 = fmaf(iw2.y, f0, a2_0);
        a2_1 = fmaf(iw2.y, f1, a2_1);
    }

    // combine the two half-waves
    a01_0.x += __shfl_xor(a01_0.x, 32, 64);
    a01_0.y += __shfl_xor(a01_0.y, 32, 64);
    a01_1.x += __shfl_xor(a01_1.x, 32, 64);
    a01_1.y += __shfl_xor(a01_1.y, 32, 64);
    a2_0 += __shfl_xor(a2_0, 32, 64);
    a2_1 += __shfl_xor(a2_1, 32, 64);

    if (h == 0 && v < V) {
        const float r0 = __builtin_amdgcn_rcpf(s0);
        const float r1 = __builtin_amdgcn_rcpf(s1);
        const float r2 = __builtin_amdgcn_rcpf(s2);
        float* o = out + (unsigned)v * 192u + (unsigned)(j << 1);
        o[0]   = a01_0.x * r0;  o[1]   = a01_1.x * r0;
        o[64]  = a01_0.y * r1;  o[65]  = a01_1.y * r1;
        o[128] = a2_0   * r2;   o[129] = a2_1   * r2;
    }
}

// Fallback (fp32 gather) if workspace can't hold the bf16 feature table.
__global__ __launch_bounds__(256) void softpixel_f32_kernel(
    const float* __restrict__ feat,
    const float* __restrict__ distsq,
    const int*   __restrict__ nidx,
    const float* __restrict__ ls_ptr,
    float*       __restrict__ out,
    int V)
{
    const int lane = threadIdx.x & 63;
    const int wv   = threadIdx.x >> 6;
    const int v    = blockIdx.x * 4 + wv;
    if (v >= V) return;

    const float ls     = ls_ptr[0];
    const float scaler = 30.0f * ls;
    const float inv_ls = 1.0f / ls;

    float w0 = 0.f, w1 = 0.f, w2 = 0.f;
    int nb = 0;
    if (lane < 32) {
        const float dsq = distsq[v * 32 + lane];
        nb = nidx[v * 32 + lane];
        const float d  = sqrtf(dsq + SP_EPS);
        const float t1 = d - inv_ls;
        const float t2 = d - 2.0f * inv_ls;
        w0 = __expf(-scaler * d  * d);
        w1 = __expf(-scaler * t1 * t1);
        w2 = __expf(-scaler * t2 * t2);
    }

    float a0 = 0.f, a1 = 0.f, a2 = 0.f;
    float s0 = SP_EPS, s1 = SP_EPS, s2 = SP_EPS;
    #pragma unroll
    for (int k = 0; k < 32; ++k) {
        const int   ik = __shfl(nb, k, 64);
        const float u0 = __shfl(w0, k, 64);
        const float u1 = __shfl(w1, k, 64);
        const float u2 = __shfl(w2, k, 64);
        const float f  = feat[(size_t)ik * 64 + lane];
        a0 = fmaf(u0, f, a0);
        a1 = fmaf(u1, f, a1);
        a2 = fmaf(u2, f, a2);
        s0 += u0; s1 += u1; s2 += u2;
    }
    float* o = out + (size_t)v * 192 + lane;
    o[0]   = a0 / s0;
    o[64]  = a1 / s1;
    o[128] = a2 / s2;
}

extern "C" void kernel_launch(void* const* d_in, const int* in_sizes, int n_in,
                              void* d_out, int out_size, void* d_ws, size_t ws_size,
                              hipStream_t stream) {
    const float* feat   = (const float*)d_in[0];   // (V, 64)
    const float* distsq = (const float*)d_in[1];   // (V, 32)
    const int*   nidx   = (const int*)d_in[2];     // (V, 32)
    const float* ls     = (const float*)d_in[3];   // scalar

    const int V = in_sizes[1] / 32;
    const int F = in_sizes[0] / V;                 // 64
    float* out = (float*)d_out;

    const size_t need = (size_t)V * F * sizeof(unsigned short);
    const int grid = (V + 3) / 4;                  // 4 vertices (waves) / block

    if ((size_t)ws_size >= need && F == 64) {
        unsigned short* fb = (unsigned short*)d_ws;
        const int n4 = V * F / 4;
        f32_to_bf16_kernel<<<(n4 + 255) / 256, 256, 0, stream>>>(feat, fb, n4);
        softpixel_pk_kernel<<<grid, 256, 0, stream>>>(fb, distsq, nidx, ls, out, V);
    } else {
        softpixel_f32_kernel<<<grid, 256, 0, stream>>>(feat, distsq, nidx, ls, out, V);
    }
}